// Round 3
// baseline (1133.784 us; speedup 1.0000x reference)
//
#include <hip/hip_runtime.h>
#include <hip/hip_bf16.h>

typedef unsigned short u16;
typedef u16 u16x8 __attribute__((ext_vector_type(8)));
typedef short s16x8 __attribute__((ext_vector_type(8)));
typedef float f32x4 __attribute__((ext_vector_type(4)));
typedef unsigned int u32;

#define NN 24
#define TT 49
#define MR 784                  // B*T = 16*49
#define SZT 4816896             // B*T*N*H
#define LDP 40                  // LDS row stride (u16 elems): 80B rows, 16B-aligned frags

__device__ inline u16 f2b(float f){
    __hip_bfloat16 b = __float2bfloat16(f);   // RNE, HW cvt on gfx950
    u16 r; __builtin_memcpy(&r, &b, 2); return r;
}
__device__ inline float sig_(float x){ return 1.f / (1.f + __expf(-x)); }
__device__ inline float tanh_(float x){ float e = __expf(2.f * x); return (e - 1.f) / (e + 1.f); }

// ---------------------------------------------------------------------------
// Fused phase 0: per block, one joint n, 64x64 output tile, ALL 9 gates.
// K = 1792 = [p | h(n-1) | h | h(n+1) | h(t-1) | g_t | g_s]   (f32 sources)
// Weights per gate: [U | Wt(768) | Ws | Zt | Zs_eff]; Zs_eff quirk: gate2 uses Zs[1].
// f32 -> bf16 conversion at LDS stage time; f32 accumulate; f32 stores.
// Epilogue: full cell update -> h_new, c_h_new. No workspace.
// ---------------------------------------------------------------------------
__global__ __launch_bounds__(256, 2) void fused_cell(
    const float* __restrict__ p,   const float* __restrict__ h,
    const float* __restrict__ c_h, const float* __restrict__ g_t,
    const float* __restrict__ c_g_t, const float* __restrict__ g_s,
    const float* __restrict__ c_g_s,
    const float* __restrict__ U,  const float* __restrict__ Wt,
    const float* __restrict__ Ws, const float* __restrict__ Zt,
    const float* __restrict__ Zs, const float* __restrict__ Bias,
    float* __restrict__ h_new, float* __restrict__ c_h_new)
{
    __shared__ u16 As[64 * LDP];
    __shared__ u16 Bs[9 * 64 * LDP];

    const int tid   = threadIdx.x;
    const int ntile = blockIdx.x, mtile = blockIdx.y, n = blockIdx.z;

    // A staging: thread -> (row 0..63, 8-wide k chunk)
    const int a_r = tid >> 2;
    const int a_c = (tid & 3) * 8;
    const int gr  = mtile * 64 + a_r;
    const bool mval = (gr < MR);
    const int ec = (gr * NN + n) * 256;
    const bool vnb = (n > 0), vna = (n < NN - 1), vtp = (gr % TT) != 0;

    // B staging: thread -> (2 k-rows, 4 cols) per gate
    const int w_r  = (tid >> 4) * 2;
    const int c0   = (tid & 15) * 4;
    const int gcol = ntile * 64 + c0;

    const int wave = tid >> 6, lane = tid & 63;
    const int lrow = lane & 15, lk = (lane >> 4) * 8;

    f32x4 acc[9][4];
    #pragma unroll
    for (int g = 0; g < 9; ++g)
        #pragma unroll
        for (int m = 0; m < 4; ++m)
            acc[g][m] = f32x4{0.f, 0.f, 0.f, 0.f};

    for (int kt = 0; kt < 56; ++kt) {
        const int K0 = kt * 32;
        __syncthreads();
        // ---- stage A (gathered, zero-padded at boundaries, f32 -> bf16)
        {
            const int seg  = K0 >> 8;
            const int koff = (K0 & 255) + a_c;
            const float* src = nullptr;
            bool valid = mval;
            switch (seg) {
                case 0: src = p   + ec + koff;                  break;
                case 1: valid &= vnb; src = h + ec - 256 + koff;        break;
                case 2: src = h   + ec + koff;                  break;
                case 3: valid &= vna; src = h + ec + 256 + koff;        break;
                case 4: valid &= vtp; src = h + ec - NN * 256 + koff;   break;
                case 5: src = g_t + ec + koff;                  break;
                default: src = g_s + ec + koff;                 break;
            }
            float4 lo = {0.f,0.f,0.f,0.f}, hi = {0.f,0.f,0.f,0.f};
            if (valid) { lo = *(const float4*)(src); hi = *(const float4*)(src + 4); }
            u16x8 w;
            w[0] = f2b(lo.x); w[1] = f2b(lo.y); w[2] = f2b(lo.z); w[3] = f2b(lo.w);
            w[4] = f2b(hi.x); w[5] = f2b(hi.y); w[6] = f2b(hi.z); w[7] = f2b(hi.w);
            *(u16x8*)(&As[a_r * LDP + a_c]) = w;
        }
        // ---- stage B for all 9 gates (transpose to [gate][col][k], f32 -> bf16)
        {
            const int kw = K0 + w_r;
            #pragma unroll
            for (int g = 0; g < 9; ++g) {
                const float* wrow;
                if (kw < 256)       wrow = U  + (size_t)((g * NN + n) * 256 + kw)          * 256;
                else if (kw < 1024) wrow = Wt + (size_t)((g * NN + n) * 768 + (kw - 256))  * 256;
                else if (kw < 1280) wrow = Ws + (size_t)((g * NN + n) * 256 + (kw - 1024)) * 256;
                else if (kw < 1536) wrow = Zt + (size_t)((g * NN + n) * 256 + (kw - 1280)) * 256;
                else {
                    const int g2 = (g == 2) ? 1 : g;   // Zs_eff: f_ft gate uses Zs[lt]
                    wrow = Zs + (size_t)((g2 * NN + n) * 256 + (kw - 1536)) * 256;
                }
                const float4 r0 = *(const float4*)(wrow + gcol);
                const float4 r1 = *(const float4*)(wrow + 256 + gcol);
                u32 pk[4];
                pk[0] = (u32)f2b(r0.x) | ((u32)f2b(r1.x) << 16);
                pk[1] = (u32)f2b(r0.y) | ((u32)f2b(r1.y) << 16);
                pk[2] = (u32)f2b(r0.z) | ((u32)f2b(r1.z) << 16);
                pk[3] = (u32)f2b(r0.w) | ((u32)f2b(r1.w) << 16);
                #pragma unroll
                for (int j = 0; j < 4; ++j)
                    *(u32*)(&Bs[(g * 64 + c0 + j) * LDP + w_r]) = pk[j];
            }
        }
        __syncthreads();
        // ---- MFMA: A frags shared across all 9 gates
        s16x8 af[4];
        #pragma unroll
        for (int m = 0; m < 4; ++m)
            af[m] = *(const s16x8*)(&As[(m * 16 + lrow) * LDP + lk]);
        #pragma unroll
        for (int g = 0; g < 9; ++g) {
            const s16x8 bf = *(const s16x8*)(&Bs[(g * 64 + wave * 16 + lrow) * LDP + lk]);
            #pragma unroll
            for (int m = 0; m < 4; ++m)
                acc[g][m] = __builtin_amdgcn_mfma_f32_16x16x32_bf16(af[m], bf, acc[g][m], 0, 0, 0);
        }
    }

    // ---- epilogue: bias + full cell elementwise update, direct f32 store
    const int col = ntile * 64 + wave * 16 + lrow;
    float bv[9];
    #pragma unroll
    for (int g = 0; g < 9; ++g) bv[g] = Bias[(g * NN + n) * 256 + col];

    #pragma unroll
    for (int m = 0; m < 4; ++m) {
        #pragma unroll
        for (int i = 0; i < 4; ++i) {
            const int row = mtile * 64 + m * 16 + (lane >> 4) * 4 + i;
            if (row < MR) {
                const size_t e = ((size_t)(row * NN + n)) * 256 + col;
                const float i_n  = sig_(acc[0][m][i] + bv[0]);
                const float f_lt = sig_(acc[1][m][i] + bv[1]);
                const float f_ft = sig_(acc[2][m][i] + bv[2]);
                const float f_rt = sig_(acc[3][m][i] + bv[3]);
                const float f_s  = sig_(acc[4][m][i] + bv[4]);
                const float f_gt = sig_(acc[5][m][i] + bv[5]);
                const float f_gs = sig_(acc[6][m][i] + bv[6]);
                const float o_n  = sig_(acc[7][m][i] + bv[7]);
                const float c_n  = tanh_(acc[8][m][i] + bv[8]);
                const float cb = (n > 0)      ? c_h[e - 256] : 0.f;
                const float ca = (n < NN - 1) ? c_h[e + 256] : 0.f;
                const float cs = (row % TT)   ? c_h[e - NN * 256] : 0.f;
                const float cn = f_lt * cb + f_ft * c_h[e] + f_rt * ca
                               + f_s * cs + f_gt * c_g_t[e] + f_gs * c_g_s[e]
                               + i_n * c_n;
                c_h_new[e] = cn;
                h_new[e]   = o_n * tanh_(cn);
            }
        }
    }
}

// ---------------------------------------------------------------------------
// Fused phase 1: per block, one (group, n), 64x64 tile, the group's 3 gates.
// K = 512 = [h_new | (group==0 ? g_t : g_s)]; weights [Wg | Zg].
// Epilogue: global gate update -> (g_t_new,c_g_t_new) or (g_s_new,c_g_s_new).
// ---------------------------------------------------------------------------
__global__ __launch_bounds__(256, 2) void fused_global(
    const float* __restrict__ hn,   const float* __restrict__ g_t,
    const float* __restrict__ g_s,  const float* __restrict__ c_g_t,
    const float* __restrict__ c_g_s,
    const float* __restrict__ Wg, const float* __restrict__ Zg,
    const float* __restrict__ Bg,
    float* __restrict__ out2, float* __restrict__ out3,
    float* __restrict__ out4, float* __restrict__ out5)
{
    __shared__ u16 As[64 * LDP];
    __shared__ u16 Bs[3 * 64 * LDP];

    const int tid   = threadIdx.x;
    const int ntile = blockIdx.x, mtile = blockIdx.y;
    const int n = blockIdx.z % NN, grp = blockIdx.z / NN;

    const float* xg  = grp ? g_s : g_t;
    const float* cg  = grp ? c_g_s : c_g_t;
    float* og  = grp ? out4 : out2;
    float* ocg = grp ? out5 : out3;

    const int a_r = tid >> 2;
    const int a_c = (tid & 3) * 8;
    const int gr  = mtile * 64 + a_r;
    const bool mval = (gr < MR);
    const int ec = (gr * NN + n) * 256;

    const int w_r  = (tid >> 4) * 2;
    const int c0   = (tid & 15) * 4;
    const int gcol = ntile * 64 + c0;

    const int wave = tid >> 6, lane = tid & 63;
    const int lrow = lane & 15, lk = (lane >> 4) * 8;

    f32x4 acc[3][4];
    #pragma unroll
    for (int g = 0; g < 3; ++g)
        #pragma unroll
        for (int m = 0; m < 4; ++m)
            acc[g][m] = f32x4{0.f, 0.f, 0.f, 0.f};

    for (int kt = 0; kt < 16; ++kt) {
        const int K0 = kt * 32;
        __syncthreads();
        {   // stage A
            const int koff = (K0 & 255) + a_c;
            const float* src = ((K0 < 256) ? hn : xg) + ec + koff;
            float4 lo = {0.f,0.f,0.f,0.f}, hi = {0.f,0.f,0.f,0.f};
            if (mval) { lo = *(const float4*)(src); hi = *(const float4*)(src + 4); }
            u16x8 w;
            w[0] = f2b(lo.x); w[1] = f2b(lo.y); w[2] = f2b(lo.z); w[3] = f2b(lo.w);
            w[4] = f2b(hi.x); w[5] = f2b(hi.y); w[6] = f2b(hi.z); w[7] = f2b(hi.w);
            *(u16x8*)(&As[a_r * LDP + a_c]) = w;
        }
        {   // stage B (3 gates)
            const int kw = K0 + w_r;
            #pragma unroll
            for (int g = 0; g < 3; ++g) {
                const int gg6 = grp * 3 + g;
                const float* wrow = (kw < 256)
                    ? Wg + (size_t)((gg6 * NN + n) * 256 + kw) * 256
                    : Zg + (size_t)((gg6 * NN + n) * 256 + (kw - 256)) * 256;
                const float4 r0 = *(const float4*)(wrow + gcol);
                const float4 r1 = *(const float4*)(wrow + 256 + gcol);
                u32 pk[4];
                pk[0] = (u32)f2b(r0.x) | ((u32)f2b(r1.x) << 16);
                pk[1] = (u32)f2b(r0.y) | ((u32)f2b(r1.y) << 16);
                pk[2] = (u32)f2b(r0.z) | ((u32)f2b(r1.z) << 16);
                pk[3] = (u32)f2b(r0.w) | ((u32)f2b(r1.w) << 16);
                #pragma unroll
                for (int j = 0; j < 4; ++j)
                    *(u32*)(&Bs[(g * 64 + c0 + j) * LDP + w_r]) = pk[j];
            }
        }
        __syncthreads();
        s16x8 af[4];
        #pragma unroll
        for (int m = 0; m < 4; ++m)
            af[m] = *(const s16x8*)(&As[(m * 16 + lrow) * LDP + lk]);
        #pragma unroll
        for (int g = 0; g < 3; ++g) {
            const s16x8 bf = *(const s16x8*)(&Bs[(g * 64 + wave * 16 + lrow) * LDP + lk]);
            #pragma unroll
            for (int m = 0; m < 4; ++m)
                acc[g][m] = __builtin_amdgcn_mfma_f32_16x16x32_bf16(af[m], bf, acc[g][m], 0, 0, 0);
        }
    }

    const int col = ntile * 64 + wave * 16 + lrow;
    float bv[3];
    #pragma unroll
    for (int g = 0; g < 3; ++g) bv[g] = Bg[((grp * 3 + g) * NN + n) * 256 + col];

    #pragma unroll
    for (int m = 0; m < 4; ++m) {
        #pragma unroll
        for (int i = 0; i < 4; ++i) {
            const int row = mtile * 64 + m * 16 + (lane >> 4) * 4 + i;
            if (row < MR) {
                const size_t e = ((size_t)(row * NN + n)) * 256 + col;
                const float f    = sig_(acc[0][m][i] + bv[0]);
                const float cand = tanh_(acc[1][m][i] + bv[1]);
                const float o    = sig_(acc[2][m][i] + bv[2]);
                const float cn = f * cg[e] + (1.f - f) * cand;
                ocg[e] = cn;
                og[e]  = o * tanh_(cn);
            }
        }
    }
}

extern "C" void kernel_launch(void* const* d_in, const int* in_sizes, int n_in,
                              void* d_out, int out_size, void* d_ws, size_t ws_size,
                              hipStream_t stream)
{
    const float* h     = (const float*)d_in[0];
    const float* c_h   = (const float*)d_in[1];
    const float* p     = (const float*)d_in[2];
    const float* g_t   = (const float*)d_in[3];
    const float* c_g_t = (const float*)d_in[4];
    const float* g_s   = (const float*)d_in[5];
    const float* c_g_s = (const float*)d_in[6];
    const float* U     = (const float*)d_in[7];
    const float* Wt    = (const float*)d_in[8];
    const float* Ws    = (const float*)d_in[9];
    const float* Zt    = (const float*)d_in[10];
    const float* Zs    = (const float*)d_in[11];
    const float* bb    = (const float*)d_in[12];
    const float* Wg    = (const float*)d_in[13];
    const float* Zg    = (const float*)d_in[14];
    const float* bg    = (const float*)d_in[15];

    float* out0 = (float*)d_out;        // h_new
    float* out1 = out0 + (size_t)SZT;   // c_h_new
    float* out2 = out1 + (size_t)SZT;   // g_t_new
    float* out3 = out2 + (size_t)SZT;   // c_g_t_new
    float* out4 = out3 + (size_t)SZT;   // g_s_new
    float* out5 = out4 + (size_t)SZT;   // c_g_s_new

    dim3 blk(256);
    fused_cell<<<dim3(4, 13, 24), blk, 0, stream>>>(
        p, h, c_h, g_t, c_g_t, g_s, c_g_s, U, Wt, Ws, Zt, Zs, bb, out0, out1);
    fused_global<<<dim3(4, 13, 48), blk, 0, stream>>>(
        out0, g_t, g_s, c_g_t, c_g_s, Wg, Zg, bg, out2, out3, out4, out5);
}

// Round 4
// 851.159 us; speedup vs baseline: 1.3320x; 1.3320x over previous
//
#include <hip/hip_runtime.h>
#include <hip/hip_bf16.h>

typedef unsigned short u16;
typedef u16 u16x8 __attribute__((ext_vector_type(8)));
typedef short s16x8 __attribute__((ext_vector_type(8)));
typedef float f32x4 __attribute__((ext_vector_type(4)));
typedef unsigned int u32;

#define NN 24
#define TT 49
#define MR 784                  // B*T = 16*49
#define SZT 4816896             // B*T*N*H
#define LDP 40                  // LDS row stride (u16): 80B rows, 16B-aligned frags
#define SWZ(r) ((((r) >> 3) & 3) << 3)   // k-XOR swizzle: conflict-free B writes

#define ABUF (64 * LDP)         // 2560 u16
#define BBUF (9 * 64 * LDP)     // 23040 u16

__device__ inline u16 f2b(float f){
    __hip_bfloat16 b = __float2bfloat16(f); u16 r; __builtin_memcpy(&r, &b, 2); return r;
}
__device__ inline u32 pk2(float a, float b){ return (u32)f2b(a) | ((u32)f2b(b) << 16); }
__device__ inline float sig_(float x){ return 1.f / (1.f + __expf(-x)); }
__device__ inline float tanh_(float x){ float e = __expf(2.f * x); return (e - 1.f) / (e + 1.f); }

// ---------------------------------------------------------------------------
// Fused phase 0: one joint n, 64x64 tile, all 9 gates. Double-buffered LDS,
// register-prefetched staging, swizzled B transpose. Epilogue = cell update.
// ---------------------------------------------------------------------------
__global__ __launch_bounds__(256, 1) void fused_cell(
    const float* __restrict__ p,   const float* __restrict__ h,
    const float* __restrict__ c_h, const float* __restrict__ g_t,
    const float* __restrict__ c_g_t, const float* __restrict__ g_s,
    const float* __restrict__ c_g_s,
    const float* __restrict__ U,  const float* __restrict__ Wt,
    const float* __restrict__ Ws, const float* __restrict__ Zt,
    const float* __restrict__ Zs, const float* __restrict__ Bias,
    float* __restrict__ h_new, float* __restrict__ c_h_new)
{
    extern __shared__ u16 smem[];   // [2*ABUF | 2*BBUF] = 102400 B

    const int tid   = threadIdx.x;
    const int mtile = blockIdx.x, ntile = blockIdx.y, n = blockIdx.z;

    // A staging map: thread -> (row 0..63, 8-wide k chunk)
    const int a_r = tid >> 2, a_c = (tid & 3) * 8;
    const int gr  = mtile * 64 + a_r;
    const bool mval = (gr < MR);
    const int ec = (gr * NN + n) * 256;
    const bool vnb = (n > 0), vna = (n < NN - 1), vtp = (gr % TT) != 0;

    // B staging map: thread -> (2 k-rows, 4 cols) per gate
    const int w_r  = (tid >> 4) * 2;
    const int c0   = (tid & 15) * 4;
    const int gcol = ntile * 64 + c0;

    const int wave = tid >> 6, lane = tid & 63;
    const int lrow = lane & 15, lk = (lane >> 4) * 8;

    // LDS offsets (precomputed)
    int aro[4];
    #pragma unroll
    for (int m = 0; m < 4; ++m) aro[m] = (m * 16 + lrow) * LDP + lk;
    const int brow = wave * 16 + lrow;
    const int bro  = brow * LDP + (lk ^ SWZ(brow));
    const int awo  = a_r * LDP + a_c;
    int bwo[4];
    #pragma unroll
    for (int j = 0; j < 4; ++j) bwo[j] = (c0 + j) * LDP + (w_r ^ SWZ(c0 + j));

    f32x4 acc[9][4];
    #pragma unroll
    for (int g = 0; g < 9; ++g)
        #pragma unroll
        for (int m = 0; m < 4; ++m) acc[g][m] = f32x4{0.f, 0.f, 0.f, 0.f};

    float4 alo, ahi, br0[9], br1[9];

    auto loadA = [&](int kt) {
        const int K0 = kt * 32, seg = K0 >> 8, koff = (K0 & 255) + a_c;
        const float* src = nullptr; bool valid = mval;
        switch (seg) {
            case 0: src = p + ec + koff; break;
            case 1: valid &= vnb; src = h + ec - 256 + koff; break;
            case 2: src = h + ec + koff; break;
            case 3: valid &= vna; src = h + ec + 256 + koff; break;
            case 4: valid &= vtp; src = h + ec - NN * 256 + koff; break;
            case 5: src = g_t + ec + koff; break;
            default: src = g_s + ec + koff; break;
        }
        alo = make_float4(0.f, 0.f, 0.f, 0.f); ahi = alo;
        if (valid) { alo = *(const float4*)src; ahi = *(const float4*)(src + 4); }
    };
    auto loadB = [&](int kt) {
        const int kw = kt * 32 + w_r;
        #pragma unroll
        for (int g = 0; g < 9; ++g) {
            const float* wrow;
            if (kw < 256)       wrow = U  + (size_t)((g * NN + n) * 256 + kw)          * 256;
            else if (kw < 1024) wrow = Wt + (size_t)((g * NN + n) * 768 + (kw - 256))  * 256;
            else if (kw < 1280) wrow = Ws + (size_t)((g * NN + n) * 256 + (kw - 1024)) * 256;
            else if (kw < 1536) wrow = Zt + (size_t)((g * NN + n) * 256 + (kw - 1280)) * 256;
            else { const int g2 = (g == 2) ? 1 : g;    // Zs_eff: f_ft uses Zs[lt]
                   wrow = Zs + (size_t)((g2 * NN + n) * 256 + (kw - 1536)) * 256; }
            br0[g] = *(const float4*)(wrow + gcol);
            br1[g] = *(const float4*)(wrow + 256 + gcol);
        }
    };
    auto store = [&](int buf) {
        u16* Asb = smem + buf * ABUF;
        u16* Bsb = smem + 2 * ABUF + buf * BBUF;
        u16x8 aw;
        aw[0] = f2b(alo.x); aw[1] = f2b(alo.y); aw[2] = f2b(alo.z); aw[3] = f2b(alo.w);
        aw[4] = f2b(ahi.x); aw[5] = f2b(ahi.y); aw[6] = f2b(ahi.z); aw[7] = f2b(ahi.w);
        *(u16x8*)(&Asb[awo]) = aw;
        #pragma unroll
        for (int g = 0; g < 9; ++g) {
            u16* bb_ = &Bsb[g * 64 * LDP];
            *(u32*)(&bb_[bwo[0]]) = pk2(br0[g].x, br1[g].x);
            *(u32*)(&bb_[bwo[1]]) = pk2(br0[g].y, br1[g].y);
            *(u32*)(&bb_[bwo[2]]) = pk2(br0[g].z, br1[g].z);
            *(u32*)(&bb_[bwo[3]]) = pk2(br0[g].w, br1[g].w);
        }
    };
    auto domfma = [&](int buf) {
        const u16* Asb = smem + buf * ABUF;
        const u16* Bsb = smem + 2 * ABUF + buf * BBUF;
        s16x8 af[4];
        #pragma unroll
        for (int m = 0; m < 4; ++m) af[m] = *(const s16x8*)(&Asb[aro[m]]);
        #pragma unroll
        for (int g = 0; g < 9; ++g) {
            const s16x8 bf = *(const s16x8*)(&Bsb[g * 64 * LDP + bro]);
            #pragma unroll
            for (int m = 0; m < 4; ++m)
                acc[g][m] = __builtin_amdgcn_mfma_f32_16x16x32_bf16(af[m], bf, acc[g][m], 0, 0, 0);
        }
    };

    // prologue: stage step 0 into buf 0
    loadA(0); loadB(0); store(0);
    for (int kt = 0; kt < 56; kt += 2) {
        __syncthreads();                       // buf0 ready; buf1 readers done
        loadA(kt + 1); loadB(kt + 1);          // prefetch k+1 (arrives under MFMA)
        domfma(0);
        store(1);                              // cvt+write overlap-scheduled w/ MFMA
        __syncthreads();                       // buf1 ready; buf0 readers done
        if (kt + 2 < 56) { loadA(kt + 2); loadB(kt + 2); }
        domfma(1);
        if (kt + 2 < 56) store(0);
    }

    // ---- epilogue: bias + cell update, f32 stores
    const int col = ntile * 64 + wave * 16 + lrow;
    float bv[9];
    #pragma unroll
    for (int g = 0; g < 9; ++g) bv[g] = Bias[(g * NN + n) * 256 + col];

    #pragma unroll
    for (int m = 0; m < 4; ++m) {
        #pragma unroll
        for (int i = 0; i < 4; ++i) {
            const int row = mtile * 64 + m * 16 + (lane >> 4) * 4 + i;
            if (row < MR) {
                const size_t e = ((size_t)(row * NN + n)) * 256 + col;
                const float i_n  = sig_(acc[0][m][i] + bv[0]);
                const float f_lt = sig_(acc[1][m][i] + bv[1]);
                const float f_ft = sig_(acc[2][m][i] + bv[2]);
                const float f_rt = sig_(acc[3][m][i] + bv[3]);
                const float f_s  = sig_(acc[4][m][i] + bv[4]);
                const float f_gt = sig_(acc[5][m][i] + bv[5]);
                const float f_gs = sig_(acc[6][m][i] + bv[6]);
                const float o_n  = sig_(acc[7][m][i] + bv[7]);
                const float c_n  = tanh_(acc[8][m][i] + bv[8]);
                const float cb = (n > 0)      ? c_h[e - 256] : 0.f;
                const float ca = (n < NN - 1) ? c_h[e + 256] : 0.f;
                const float cs = (row % TT)   ? c_h[e - NN * 256] : 0.f;
                const float cn = f_lt * cb + f_ft * c_h[e] + f_rt * ca
                               + f_s * cs + f_gt * c_g_t[e] + f_gs * c_g_s[e]
                               + i_n * c_n;
                c_h_new[e] = cn;
                h_new[e]   = o_n * tanh_(cn);
            }
        }
    }
}

// ---------------------------------------------------------------------------
// Fused phase 1: one (group, n), 64x64 tile, 3 gates. Same pipelined scheme.
// ---------------------------------------------------------------------------
__global__ __launch_bounds__(256, 2) void fused_global(
    const float* __restrict__ hn,   const float* __restrict__ g_t,
    const float* __restrict__ g_s,  const float* __restrict__ c_g_t,
    const float* __restrict__ c_g_s,
    const float* __restrict__ Wg, const float* __restrict__ Zg,
    const float* __restrict__ Bg,
    float* __restrict__ out2, float* __restrict__ out3,
    float* __restrict__ out4, float* __restrict__ out5)
{
    __shared__ u16 As2[2][64 * LDP];
    __shared__ u16 Bs2[2][3 * 64 * LDP];

    const int tid   = threadIdx.x;
    const int mtile = blockIdx.x, ntile = blockIdx.y;
    const int n = blockIdx.z % NN, grp = blockIdx.z / NN;

    const float* xg = grp ? g_s : g_t;
    const float* cg = grp ? c_g_s : c_g_t;
    float* og  = grp ? out4 : out2;
    float* ocg = grp ? out5 : out3;

    const int a_r = tid >> 2, a_c = (tid & 3) * 8;
    const int gr  = mtile * 64 + a_r;
    const bool mval = (gr < MR);
    const int ec = (gr * NN + n) * 256;

    const int w_r  = (tid >> 4) * 2;
    const int c0   = (tid & 15) * 4;
    const int gcol = ntile * 64 + c0;

    const int wave = tid >> 6, lane = tid & 63;
    const int lrow = lane & 15, lk = (lane >> 4) * 8;

    int aro[4];
    #pragma unroll
    for (int m = 0; m < 4; ++m) aro[m] = (m * 16 + lrow) * LDP + lk;
    const int brow = wave * 16 + lrow;
    const int bro  = brow * LDP + (lk ^ SWZ(brow));
    const int awo  = a_r * LDP + a_c;
    int bwo[4];
    #pragma unroll
    for (int j = 0; j < 4; ++j) bwo[j] = (c0 + j) * LDP + (w_r ^ SWZ(c0 + j));

    f32x4 acc[3][4];
    #pragma unroll
    for (int g = 0; g < 3; ++g)
        #pragma unroll
        for (int m = 0; m < 4; ++m) acc[g][m] = f32x4{0.f, 0.f, 0.f, 0.f};

    float4 alo, ahi, br0[3], br1[3];

    auto loadA = [&](int kt) {
        const int K0 = kt * 32, koff = (K0 & 255) + a_c;
        const float* src = ((K0 < 256) ? hn : xg) + ec + koff;
        alo = make_float4(0.f, 0.f, 0.f, 0.f); ahi = alo;
        if (mval) { alo = *(const float4*)src; ahi = *(const float4*)(src + 4); }
    };
    auto loadB = [&](int kt) {
        const int kw = kt * 32 + w_r;
        #pragma unroll
        for (int g = 0; g < 3; ++g) {
            const int gg6 = grp * 3 + g;
            const float* wrow = (kw < 256)
                ? Wg + (size_t)((gg6 * NN + n) * 256 + kw) * 256
                : Zg + (size_t)((gg6 * NN + n) * 256 + (kw - 256)) * 256;
            br0[g] = *(const float4*)(wrow + gcol);
            br1[g] = *(const float4*)(wrow + 256 + gcol);
        }
    };
    auto store = [&](int buf) {
        u16x8 aw;
        aw[0] = f2b(alo.x); aw[1] = f2b(alo.y); aw[2] = f2b(alo.z); aw[3] = f2b(alo.w);
        aw[4] = f2b(ahi.x); aw[5] = f2b(ahi.y); aw[6] = f2b(ahi.z); aw[7] = f2b(ahi.w);
        *(u16x8*)(&As2[buf][awo]) = aw;
        #pragma unroll
        for (int g = 0; g < 3; ++g) {
            u16* bb_ = &Bs2[buf][g * 64 * LDP];
            *(u32*)(&bb_[bwo[0]]) = pk2(br0[g].x, br1[g].x);
            *(u32*)(&bb_[bwo[1]]) = pk2(br0[g].y, br1[g].y);
            *(u32*)(&bb_[bwo[2]]) = pk2(br0[g].z, br1[g].z);
            *(u32*)(&bb_[bwo[3]]) = pk2(br0[g].w, br1[g].w);
        }
    };
    auto domfma = [&](int buf) {
        s16x8 af[4];
        #pragma unroll
        for (int m = 0; m < 4; ++m) af[m] = *(const s16x8*)(&As2[buf][aro[m]]);
        #pragma unroll
        for (int g = 0; g < 3; ++g) {
            const s16x8 bf = *(const s16x8*)(&Bs2[buf][g * 64 * LDP + bro]);
            #pragma unroll
            for (int m = 0; m < 4; ++m)
                acc[g][m] = __builtin_amdgcn_mfma_f32_16x16x32_bf16(af[m], bf, acc[g][m], 0, 0, 0);
        }
    };

    loadA(0); loadB(0); store(0);
    for (int kt = 0; kt < 16; kt += 2) {
        __syncthreads();
        loadA(kt + 1); loadB(kt + 1);
        domfma(0);
        store(1);
        __syncthreads();
        if (kt + 2 < 16) { loadA(kt + 2); loadB(kt + 2); }
        domfma(1);
        if (kt + 2 < 16) store(0);
    }

    const int col = ntile * 64 + wave * 16 + lrow;
    float bv[3];
    #pragma unroll
    for (int g = 0; g < 3; ++g) bv[g] = Bg[((grp * 3 + g) * NN + n) * 256 + col];

    #pragma unroll
    for (int m = 0; m < 4; ++m) {
        #pragma unroll
        for (int i = 0; i < 4; ++i) {
            const int row = mtile * 64 + m * 16 + (lane >> 4) * 4 + i;
            if (row < MR) {
                const size_t e = ((size_t)(row * NN + n)) * 256 + col;
                const float f    = sig_(acc[0][m][i] + bv[0]);
                const float cand = tanh_(acc[1][m][i] + bv[1]);
                const float o    = sig_(acc[2][m][i] + bv[2]);
                const float cn = f * cg[e] + (1.f - f) * cand;
                ocg[e] = cn;
                og[e]  = o * tanh_(cn);
            }
        }
    }
}

extern "C" void kernel_launch(void* const* d_in, const int* in_sizes, int n_in,
                              void* d_out, int out_size, void* d_ws, size_t ws_size,
                              hipStream_t stream)
{
    const float* h     = (const float*)d_in[0];
    const float* c_h   = (const float*)d_in[1];
    const float* p     = (const float*)d_in[2];
    const float* g_t   = (const float*)d_in[3];
    const float* c_g_t = (const float*)d_in[4];
    const float* g_s   = (const float*)d_in[5];
    const float* c_g_s = (const float*)d_in[6];
    const float* U     = (const float*)d_in[7];
    const float* Wt    = (const float*)d_in[8];
    const float* Ws    = (const float*)d_in[9];
    const float* Zt    = (const float*)d_in[10];
    const float* Zs    = (const float*)d_in[11];
    const float* bb    = (const float*)d_in[12];
    const float* Wg    = (const float*)d_in[13];
    const float* Zg    = (const float*)d_in[14];
    const float* bg    = (const float*)d_in[15];

    float* out0 = (float*)d_out;        // h_new
    float* out1 = out0 + (size_t)SZT;   // c_h_new
    float* out2 = out1 + (size_t)SZT;   // g_t_new
    float* out3 = out2 + (size_t)SZT;   // c_g_t_new
    float* out4 = out3 + (size_t)SZT;   // g_s_new
    float* out5 = out4 + (size_t)SZT;   // c_g_s_new

    const int dynLds = 2 * (ABUF + BBUF) * (int)sizeof(u16);   // 102400 B
    hipFuncSetAttribute((const void*)fused_cell,
                        hipFuncAttributeMaxDynamicSharedMemorySize, dynLds);

    dim3 blk(256);
    fused_cell<<<dim3(13, 4, 24), blk, dynLds, stream>>>(
        p, h, c_h, g_t, c_g_t, g_s, c_g_s, U, Wt, Ws, Zt, Zs, bb, out0, out1);
    fused_global<<<dim3(13, 4, 48), blk, 0, stream>>>(
        out0, g_t, g_s, c_g_t, c_g_s, Wg, Zg, bg, out2, out3, out4, out5);
}

// Round 5
// 661.200 us; speedup vs baseline: 1.7147x; 1.2873x over previous
//
#include <hip/hip_runtime.h>
#include <hip/hip_bf16.h>

typedef unsigned short u16;
typedef u16 u16x8 __attribute__((ext_vector_type(8)));
typedef short s16x8 __attribute__((ext_vector_type(8)));
typedef float f32x4 __attribute__((ext_vector_type(4)));
typedef unsigned int u32;

#define NN 24
#define TT 49
#define MR 784                  // B*T = 16*49
#define SZT 4816896             // B*T*N*H

__device__ inline u16 f2b(float f){
    __hip_bfloat16 b = __float2bfloat16(f); u16 r; __builtin_memcpy(&r, &b, 2); return r;
}
__device__ inline u32 pk2(float a, float b){ return (u32)f2b(a) | ((u32)f2b(b) << 16); }
__device__ inline float sig_(float x){ return 1.f / (1.f + __expf(-x)); }
__device__ inline float tanh_(float x){ float e = __expf(2.f * x); return (e - 1.f) / (e + 1.f); }

// ws layout: WT0 bf16 [216][256][1792], WT1 bf16 [144][256][512]
#define WT0_ELEMS ((size_t)216 * 256 * 1792)
#define WT1_ELEMS ((size_t)144 * 256 * 512)
#define WS_NEED   ((WT0_ELEMS + WT1_ELEMS) * 2)

// ===========================================================================
// Prepass: weight f32 [k][col] -> bf16 [col][k], k-concatenated per slab.
// ===========================================================================
__global__ __launch_bounds__(256) void wprep0(
    const float* __restrict__ U,  const float* __restrict__ Wt,
    const float* __restrict__ Ws, const float* __restrict__ Zt,
    const float* __restrict__ Zs, u16* __restrict__ out)
{
    __shared__ u16 T[64][72];
    const int tid = threadIdx.x;
    const int kt = blockIdx.x, ct = blockIdx.y, z = blockIdx.z;
    const int n = z % NN, g = z / NN;
    const int k0 = kt * 64;

    const float* wbase;           // points at row k0 of the segment, 256-col rows
    if (k0 < 256)       wbase = U  + (size_t)((g * NN + n) * 256 + k0)          * 256;
    else if (k0 < 1024) wbase = Wt + (size_t)((g * NN + n) * 768 + (k0 - 256))  * 256;
    else if (k0 < 1280) wbase = Ws + (size_t)((g * NN + n) * 256 + (k0 - 1024)) * 256;
    else if (k0 < 1536) wbase = Zt + (size_t)((g * NN + n) * 256 + (k0 - 1280)) * 256;
    else { const int g2 = (g == 2) ? 1 : g;      // Zs_eff: f_ft uses Zs[lt]
           wbase = Zs + (size_t)((g2 * NN + n) * 256 + (k0 - 1536)) * 256; }

    const int colg = ct * 64 + (tid & 15) * 4;
    #pragma unroll
    for (int it = 0; it < 4; ++it) {
        const int krl = (tid >> 4) + it * 16;
        const float4 v = *(const float4*)(wbase + (size_t)krl * 256 + colg);
        const int cl = (tid & 15) * 4;
        T[cl + 0][krl] = f2b(v.x); T[cl + 1][krl] = f2b(v.y);
        T[cl + 2][krl] = f2b(v.z); T[cl + 3][krl] = f2b(v.w);
    }
    __syncthreads();
    const int col_l = tid >> 2, ks = (tid & 3) * 16;
    u16* dst = out + ((size_t)z * 256 + ct * 64 + col_l) * 1792 + kt * 64 + ks;
    u16x8 w0, w1;
    #pragma unroll
    for (int j = 0; j < 8; ++j) { w0[j] = T[col_l][ks + j]; w1[j] = T[col_l][ks + 8 + j]; }
    *(u16x8*)(dst) = w0; *(u16x8*)(dst + 8) = w1;
}

__global__ __launch_bounds__(256) void wprep1(
    const float* __restrict__ Wg, const float* __restrict__ Zg, u16* __restrict__ out)
{
    __shared__ u16 T[64][72];
    const int tid = threadIdx.x;
    const int kt = blockIdx.x, ct = blockIdx.y, z = blockIdx.z;
    const int n = z % NN, gg6 = z / NN;
    const int k0 = kt * 64;
    const float* wbase = (k0 < 256)
        ? Wg + (size_t)((gg6 * NN + n) * 256 + k0) * 256
        : Zg + (size_t)((gg6 * NN + n) * 256 + (k0 - 256)) * 256;

    const int colg = ct * 64 + (tid & 15) * 4;
    #pragma unroll
    for (int it = 0; it < 4; ++it) {
        const int krl = (tid >> 4) + it * 16;
        const float4 v = *(const float4*)(wbase + (size_t)krl * 256 + colg);
        const int cl = (tid & 15) * 4;
        T[cl + 0][krl] = f2b(v.x); T[cl + 1][krl] = f2b(v.y);
        T[cl + 2][krl] = f2b(v.z); T[cl + 3][krl] = f2b(v.w);
    }
    __syncthreads();
    const int col_l = tid >> 2, ks = (tid & 3) * 16;
    u16* dst = out + ((size_t)z * 256 + ct * 64 + col_l) * 512 + kt * 64 + ks;
    u16x8 w0, w1;
    #pragma unroll
    for (int j = 0; j < 8; ++j) { w0[j] = T[col_l][ks + j]; w1[j] = T[col_l][ks + 8 + j]; }
    *(u16x8*)(dst) = w0; *(u16x8*)(dst + 8) = w1;
}

// ===========================================================================
// Fast path phase 0: 64x64 tile, 9 gates, B from pre-transposed bf16 weights.
// LDS: dbuf A (64x32) + dbuf B (9x64x32), 64B rows, XOR slot swizzle. 81920 B.
// ===========================================================================
#define AB2 2048                 // elems per A buf
#define BB2 18432                // elems per B buf (9*2048)

__global__ __launch_bounds__(256, 2) void fused_cell2(
    const float* __restrict__ p,   const float* __restrict__ h,
    const float* __restrict__ c_h, const float* __restrict__ g_t,
    const float* __restrict__ c_g_t, const float* __restrict__ g_s,
    const float* __restrict__ c_g_s,
    const u16* __restrict__ WT0, const float* __restrict__ Bias,
    float* __restrict__ h_new, float* __restrict__ c_h_new)
{
    extern __shared__ u16 smem[];   // [A0|A1|B0|B1] = 40960 elems

    const int tid   = threadIdx.x;
    const int mtile = blockIdx.x, ntile = blockIdx.y, n = blockIdx.z;

    // staging maps: thread -> (row/col = tid>>2, k-chunk = tid&3)
    const int s_r = tid >> 2, s_c = tid & 3;
    const int gr  = mtile * 64 + s_r;
    const bool mval = (gr < MR);
    const int ec = (gr * NN + n) * 256;
    const bool vnb = (n > 0), vna = (n < NN - 1), vtp = (gr % TT) != 0;

    // swizzled write offset (u16 elems): row*32 + ((chunk ^ ((row>>1)&3))<<3)
    const int wro = s_r * 32 + (((s_c) ^ ((s_r >> 1) & 3)) << 3);
    // B global: col = s_r (0..63), 8-k chunk = s_c
    const size_t bgo = (size_t)(ntile * 64 + s_r) * 1792 + s_c * 8;

    const int wave = tid >> 6, lane = tid & 63;
    const int lrow = lane & 15, lci = lane >> 4;     // chunk idx for frags

    int aro[4];
    #pragma unroll
    for (int m = 0; m < 4; ++m) {
        const int row = m * 16 + lrow;
        aro[m] = row * 32 + ((lci ^ ((row >> 1) & 3)) << 3);
    }
    const int colr = wave * 16 + lrow;
    const int bro  = colr * 32 + ((lci ^ ((colr >> 1) & 3)) << 3);

    f32x4 acc[9][4];
    #pragma unroll
    for (int g = 0; g < 9; ++g)
        #pragma unroll
        for (int m = 0; m < 4; ++m) acc[g][m] = f32x4{0.f, 0.f, 0.f, 0.f};

    float4 alo, ahi; u16x8 brw[9];

    auto loadA = [&](int kt) {
        const int K0 = kt * 32, seg = K0 >> 8, koff = (K0 & 255) + s_c * 8;
        const float* src = nullptr; bool valid = mval;
        switch (seg) {
            case 0: src = p + ec + koff; break;
            case 1: valid &= vnb; src = h + ec - 256 + koff; break;
            case 2: src = h + ec + koff; break;
            case 3: valid &= vna; src = h + ec + 256 + koff; break;
            case 4: valid &= vtp; src = h + ec - NN * 256 + koff; break;
            case 5: src = g_t + ec + koff; break;
            default: src = g_s + ec + koff; break;
        }
        alo = make_float4(0.f, 0.f, 0.f, 0.f); ahi = alo;
        if (valid) { alo = *(const float4*)src; ahi = *(const float4*)(src + 4); }
    };
    auto loadB = [&](int kt) {
        const u16* wb = WT0 + (size_t)n * 458752 + kt * 32 + bgo;  // n*256*1792
        #pragma unroll
        for (int g = 0; g < 9; ++g)
            brw[g] = *(const u16x8*)(wb + (size_t)g * 11010048);   // g*24*256*1792
    };
    auto store = [&](int buf) {
        u16* Asb = smem + buf * AB2;
        u16* Bsb = smem + 2 * AB2 + buf * BB2;
        u16x8 aw;
        aw[0] = f2b(alo.x); aw[1] = f2b(alo.y); aw[2] = f2b(alo.z); aw[3] = f2b(alo.w);
        aw[4] = f2b(ahi.x); aw[5] = f2b(ahi.y); aw[6] = f2b(ahi.z); aw[7] = f2b(ahi.w);
        *(u16x8*)(&Asb[wro]) = aw;
        #pragma unroll
        for (int g = 0; g < 9; ++g)
            *(u16x8*)(&Bsb[g * 2048 + wro]) = brw[g];
    };
    auto domfma = [&](int buf) {
        const u16* Asb = smem + buf * AB2;
        const u16* Bsb = smem + 2 * AB2 + buf * BB2;
        s16x8 af[4];
        #pragma unroll
        for (int m = 0; m < 4; ++m) af[m] = *(const s16x8*)(&Asb[aro[m]]);
        #pragma unroll
        for (int g = 0; g < 9; ++g) {
            const s16x8 bf = *(const s16x8*)(&Bsb[g * 2048 + bro]);
            #pragma unroll
            for (int m = 0; m < 4; ++m)
                acc[g][m] = __builtin_amdgcn_mfma_f32_16x16x32_bf16(af[m], bf, acc[g][m], 0, 0, 0);
        }
    };

    loadA(0); loadB(0); store(0);
    for (int kt = 0; kt < 56; kt += 2) {
        __syncthreads();
        loadA(kt + 1); loadB(kt + 1);
        domfma(0);
        store(1);
        __syncthreads();
        if (kt + 2 < 56) { loadA(kt + 2); loadB(kt + 2); }
        domfma(1);
        if (kt + 2 < 56) store(0);
    }

    // ---- epilogue: bias + cell update, f32 stores
    const int col = ntile * 64 + wave * 16 + lrow;
    float bv[9];
    #pragma unroll
    for (int g = 0; g < 9; ++g) bv[g] = Bias[(g * NN + n) * 256 + col];

    #pragma unroll
    for (int m = 0; m < 4; ++m) {
        #pragma unroll
        for (int i = 0; i < 4; ++i) {
            const int row = mtile * 64 + m * 16 + (lane >> 4) * 4 + i;
            if (row < MR) {
                const size_t e = ((size_t)(row * NN + n)) * 256 + col;
                const float i_n  = sig_(acc[0][m][i] + bv[0]);
                const float f_lt = sig_(acc[1][m][i] + bv[1]);
                const float f_ft = sig_(acc[2][m][i] + bv[2]);
                const float f_rt = sig_(acc[3][m][i] + bv[3]);
                const float f_s  = sig_(acc[4][m][i] + bv[4]);
                const float f_gt = sig_(acc[5][m][i] + bv[5]);
                const float f_gs = sig_(acc[6][m][i] + bv[6]);
                const float o_n  = sig_(acc[7][m][i] + bv[7]);
                const float c_n  = tanh_(acc[8][m][i] + bv[8]);
                const float cb = (n > 0)      ? c_h[e - 256] : 0.f;
                const float ca = (n < NN - 1) ? c_h[e + 256] : 0.f;
                const float cs = (row % TT)   ? c_h[e - NN * 256] : 0.f;
                const float cn = f_lt * cb + f_ft * c_h[e] + f_rt * ca
                               + f_s * cs + f_gt * c_g_t[e] + f_gs * c_g_s[e]
                               + i_n * c_n;
                c_h_new[e] = cn;
                h_new[e]   = o_n * tanh_(cn);
            }
        }
    }
}

// ===========================================================================
// Fast path phase 1: 64x64 tile, 3 gates, K=512. Static LDS 32768 B.
// ===========================================================================
__global__ __launch_bounds__(256, 3) void fused_global2(
    const float* __restrict__ hn,   const float* __restrict__ g_t,
    const float* __restrict__ g_s,  const float* __restrict__ c_g_t,
    const float* __restrict__ c_g_s,
    const u16* __restrict__ WT1, const float* __restrict__ Bg,
    float* __restrict__ out2, float* __restrict__ out3,
    float* __restrict__ out4, float* __restrict__ out5)
{
    __shared__ u16 smem[2 * 2048 + 2 * 6144];

    const int tid   = threadIdx.x;
    const int mtile = blockIdx.x, ntile = blockIdx.y;
    const int n = blockIdx.z % NN, grp = blockIdx.z / NN;

    const float* xg = grp ? g_s : g_t;
    const float* cg = grp ? c_g_s : c_g_t;
    float* og  = grp ? out4 : out2;
    float* ocg = grp ? out5 : out3;

    const int s_r = tid >> 2, s_c = tid & 3;
    const int gr  = mtile * 64 + s_r;
    const bool mval = (gr < MR);
    const int ec = (gr * NN + n) * 256;

    const int wro = s_r * 32 + (((s_c) ^ ((s_r >> 1) & 3)) << 3);
    const size_t bgo = (size_t)(ntile * 64 + s_r) * 512 + s_c * 8;

    const int wave = tid >> 6, lane = tid & 63;
    const int lrow = lane & 15, lci = lane >> 4;

    int aro[4];
    #pragma unroll
    for (int m = 0; m < 4; ++m) {
        const int row = m * 16 + lrow;
        aro[m] = row * 32 + ((lci ^ ((row >> 1) & 3)) << 3);
    }
    const int colr = wave * 16 + lrow;
    const int bro  = colr * 32 + ((lci ^ ((colr >> 1) & 3)) << 3);

    f32x4 acc[3][4];
    #pragma unroll
    for (int g = 0; g < 3; ++g)
        #pragma unroll
        for (int m = 0; m < 4; ++m) acc[g][m] = f32x4{0.f, 0.f, 0.f, 0.f};

    float4 alo, ahi; u16x8 brw[3];

    auto loadA = [&](int kt) {
        const int K0 = kt * 32, koff = (K0 & 255) + s_c * 8;
        const float* src = ((K0 < 256) ? hn : xg) + ec + koff;
        alo = make_float4(0.f, 0.f, 0.f, 0.f); ahi = alo;
        if (mval) { alo = *(const float4*)src; ahi = *(const float4*)(src + 4); }
    };
    auto loadB = [&](int kt) {
        const u16* wb = WT1 + (size_t)(grp * 3 * NN + n) * 131072 + kt * 32 + bgo; // slab*256*512
        #pragma unroll
        for (int g = 0; g < 3; ++g)
            brw[g] = *(const u16x8*)(wb + (size_t)g * NN * 131072);
    };
    auto store = [&](int buf) {
        u16* Asb = smem + buf * 2048;
        u16* Bsb = smem + 2 * 2048 + buf * 6144;
        u16x8 aw;
        aw[0] = f2b(alo.x); aw[1] = f2b(alo.y); aw[2] = f2b(alo.z); aw[3] = f2b(alo.w);
        aw[4] = f2b(ahi.x); aw[5] = f2b(ahi.y); aw[6] = f2b(ahi.z); aw[7] = f2b(ahi.w);
        *(u16x8*)(&Asb[wro]) = aw;
        #pragma unroll
        for (int g = 0; g < 3; ++g)
            *(u16x8*)(&Bsb[g * 2048 + wro]) = brw[g];
    };
    auto domfma = [&](int buf) {
        const u16* Asb = smem + buf * 2048;
        const u16* Bsb = smem + 2 * 2048 + buf * 6144;
        s16x8 af[4];
        #pragma unroll
        for (int m = 0; m < 4; ++m) af[m] = *(const s16x8*)(&Asb[aro[m]]);
        #pragma unroll
        for (int g = 0; g < 3; ++g) {
            const s16x8 bf = *(const s16x8*)(&Bsb[g * 2048 + bro]);
            #pragma unroll
            for (int m = 0; m < 4; ++m)
                acc[g][m] = __builtin_amdgcn_mfma_f32_16x16x32_bf16(af[m], bf, acc[g][m], 0, 0, 0);
        }
    };

    loadA(0); loadB(0); store(0);
    for (int kt = 0; kt < 16; kt += 2) {
        __syncthreads();
        loadA(kt + 1); loadB(kt + 1);
        domfma(0);
        store(1);
        __syncthreads();
        if (kt + 2 < 16) { loadA(kt + 2); loadB(kt + 2); }
        domfma(1);
        if (kt + 2 < 16) store(0);
    }

    const int col = ntile * 64 + wave * 16 + lrow;
    float bv[3];
    #pragma unroll
    for (int g = 0; g < 3; ++g) bv[g] = Bg[((grp * 3 + g) * NN + n) * 256 + col];

    #pragma unroll
    for (int m = 0; m < 4; ++m) {
        #pragma unroll
        for (int i = 0; i < 4; ++i) {
            const int row = mtile * 64 + m * 16 + (lane >> 4) * 4 + i;
            if (row < MR) {
                const size_t e = ((size_t)(row * NN + n)) * 256 + col;
                const float f    = sig_(acc[0][m][i] + bv[0]);
                const float cand = tanh_(acc[1][m][i] + bv[1]);
                const float o    = sig_(acc[2][m][i] + bv[2]);
                const float cn = f * cg[e] + (1.f - f) * cand;
                ocg[e] = cn;
                og[e]  = o * tanh_(cn);
            }
        }
    }
}

// ===========================================================================
// Fallback path (round-4 kernels, unchanged) — used if ws_size < WS_NEED.
// ===========================================================================
#define LDP 40
#define SWZ(r) ((((r) >> 3) & 3) << 3)
#define ABUF (64 * LDP)
#define BBUF (9 * 64 * LDP)

__global__ __launch_bounds__(256, 1) void fused_cell_fb(
    const float* __restrict__ p,   const float* __restrict__ h,
    const float* __restrict__ c_h, const float* __restrict__ g_t,
    const float* __restrict__ c_g_t, const float* __restrict__ g_s,
    const float* __restrict__ c_g_s,
    const float* __restrict__ U,  const float* __restrict__ Wt,
    const float* __restrict__ Ws, const float* __restrict__ Zt,
    const float* __restrict__ Zs, const float* __restrict__ Bias,
    float* __restrict__ h_new, float* __restrict__ c_h_new)
{
    extern __shared__ u16 smem[];
    const int tid   = threadIdx.x;
    const int mtile = blockIdx.x, ntile = blockIdx.y, n = blockIdx.z;
    const int a_r = tid >> 2, a_c = (tid & 3) * 8;
    const int gr  = mtile * 64 + a_r;
    const bool mval = (gr < MR);
    const int ec = (gr * NN + n) * 256;
    const bool vnb = (n > 0), vna = (n < NN - 1), vtp = (gr % TT) != 0;
    const int w_r  = (tid >> 4) * 2;
    const int c0   = (tid & 15) * 4;
    const int gcol = ntile * 64 + c0;
    const int wave = tid >> 6, lane = tid & 63;
    const int lrow = lane & 15, lk = (lane >> 4) * 8;
    int aro[4];
    #pragma unroll
    for (int m = 0; m < 4; ++m) aro[m] = (m * 16 + lrow) * LDP + lk;
    const int brow = wave * 16 + lrow;
    const int bro  = brow * LDP + (lk ^ SWZ(brow));
    const int awo  = a_r * LDP + a_c;
    int bwo[4];
    #pragma unroll
    for (int j = 0; j < 4; ++j) bwo[j] = (c0 + j) * LDP + (w_r ^ SWZ(c0 + j));
    f32x4 acc[9][4];
    #pragma unroll
    for (int g = 0; g < 9; ++g)
        #pragma unroll
        for (int m = 0; m < 4; ++m) acc[g][m] = f32x4{0.f, 0.f, 0.f, 0.f};
    float4 alo, ahi, br0[9], br1[9];
    auto loadA = [&](int kt) {
        const int K0 = kt * 32, seg = K0 >> 8, koff = (K0 & 255) + a_c;
        const float* src = nullptr; bool valid = mval;
        switch (seg) {
            case 0: src = p + ec + koff; break;
            case 1: valid &= vnb; src = h + ec - 256 + koff; break;
            case 2: src = h + ec + koff; break;
            case 3: valid &= vna; src = h + ec + 256 + koff; break;
            case 4: valid &= vtp; src = h + ec - NN * 256 + koff; break;
            case 5: src = g_t + ec + koff; break;
            default: src = g_s + ec + koff; break;
        }
        alo = make_float4(0.f, 0.f, 0.f, 0.f); ahi = alo;
        if (valid) { alo = *(const float4*)src; ahi = *(const float4*)(src + 4); }
    };
    auto loadB = [&](int kt) {
        const int kw = kt * 32 + w_r;
        #pragma unroll
        for (int g = 0; g < 9; ++g) {
            const float* wrow;
            if (kw < 256)       wrow = U  + (size_t)((g * NN + n) * 256 + kw)          * 256;
            else if (kw < 1024) wrow = Wt + (size_t)((g * NN + n) * 768 + (kw - 256))  * 256;
            else if (kw < 1280) wrow = Ws + (size_t)((g * NN + n) * 256 + (kw - 1024)) * 256;
            else if (kw < 1536) wrow = Zt + (size_t)((g * NN + n) * 256 + (kw - 1280)) * 256;
            else { const int g2 = (g == 2) ? 1 : g;
                   wrow = Zs + (size_t)((g2 * NN + n) * 256 + (kw - 1536)) * 256; }
            br0[g] = *(const float4*)(wrow + gcol);
            br1[g] = *(const float4*)(wrow + 256 + gcol);
        }
    };
    auto store = [&](int buf) {
        u16* Asb = smem + buf * ABUF;
        u16* Bsb = smem + 2 * ABUF + buf * BBUF;
        u16x8 aw;
        aw[0] = f2b(alo.x); aw[1] = f2b(alo.y); aw[2] = f2b(alo.z); aw[3] = f2b(alo.w);
        aw[4] = f2b(ahi.x); aw[5] = f2b(ahi.y); aw[6] = f2b(ahi.z); aw[7] = f2b(ahi.w);
        *(u16x8*)(&Asb[awo]) = aw;
        #pragma unroll
        for (int g = 0; g < 9; ++g) {
            u16* bb_ = &Bsb[g * 64 * LDP];
            *(u32*)(&bb_[bwo[0]]) = pk2(br0[g].x, br1[g].x);
            *(u32*)(&bb_[bwo[1]]) = pk2(br0[g].y, br1[g].y);
            *(u32*)(&bb_[bwo[2]]) = pk2(br0[g].z, br1[g].z);
            *(u32*)(&bb_[bwo[3]]) = pk2(br0[g].w, br1[g].w);
        }
    };
    auto domfma = [&](int buf) {
        const u16* Asb = smem + buf * ABUF;
        const u16* Bsb = smem + 2 * ABUF + buf * BBUF;
        s16x8 af[4];
        #pragma unroll
        for (int m = 0; m < 4; ++m) af[m] = *(const s16x8*)(&Asb[aro[m]]);
        #pragma unroll
        for (int g = 0; g < 9; ++g) {
            const s16x8 bf = *(const s16x8*)(&Bsb[g * 64 * LDP + bro]);
            #pragma unroll
            for (int m = 0; m < 4; ++m)
                acc[g][m] = __builtin_amdgcn_mfma_f32_16x16x32_bf16(af[m], bf, acc[g][m], 0, 0, 0);
        }
    };
    loadA(0); loadB(0); store(0);
    for (int kt = 0; kt < 56; kt += 2) {
        __syncthreads();
        loadA(kt + 1); loadB(kt + 1);
        domfma(0); store(1);
        __syncthreads();
        if (kt + 2 < 56) { loadA(kt + 2); loadB(kt + 2); }
        domfma(1);
        if (kt + 2 < 56) store(0);
    }
    const int col = ntile * 64 + wave * 16 + lrow;
    float bv[9];
    #pragma unroll
    for (int g = 0; g < 9; ++g) bv[g] = Bias[(g * NN + n) * 256 + col];
    #pragma unroll
    for (int m = 0; m < 4; ++m) {
        #pragma unroll
        for (int i = 0; i < 4; ++i) {
            const int row = mtile * 64 + m * 16 + (lane >> 4) * 4 + i;
            if (row < MR) {
                const size_t e = ((size_t)(row * NN + n)) * 256 + col;
                const float i_n  = sig_(acc[0][m][i] + bv[0]);
                const float f_lt = sig_(acc[1][m][i] + bv[1]);
                const float f_ft = sig_(acc[2][m][i] + bv[2]);
                const float f_rt = sig_(acc[3][m][i] + bv[3]);
                const float f_s  = sig_(acc[4][m][i] + bv[4]);
                const float f_gt = sig_(acc[5][m][i] + bv[5]);
                const float f_gs = sig_(acc[6][m][i] + bv[6]);
                const float o_n  = sig_(acc[7][m][i] + bv[7]);
                const float c_n  = tanh_(acc[8][m][i] + bv[8]);
                const float cb = (n > 0)      ? c_h[e - 256] : 0.f;
                const float ca = (n < NN - 1) ? c_h[e + 256] : 0.f;
                const float cs = (row % TT)   ? c_h[e - NN * 256] : 0.f;
                const float cn = f_lt * cb + f_ft * c_h[e] + f_rt * ca
                               + f_s * cs + f_gt * c_g_t[e] + f_gs * c_g_s[e]
                               + i_n * c_n;
                c_h_new[e] = cn;
                h_new[e]   = o_n * tanh_(cn);
            }
        }
    }
}

__global__ __launch_bounds__(256, 2) void fused_global_fb(
    const float* __restrict__ hn,   const float* __restrict__ g_t,
    const float* __restrict__ g_s,  const float* __restrict__ c_g_t,
    const float* __restrict__ c_g_s,
    const float* __restrict__ Wg, const float* __restrict__ Zg,
    const float* __restrict__ Bg,
    float* __restrict__ out2, float* __restrict__ out3,
    float* __restrict__ out4, float* __restrict__ out5)
{
    __shared__ u16 As2[2][64 * LDP];
    __shared__ u16 Bs2[2][3 * 64 * LDP];
    const int tid   = threadIdx.x;
    const int mtile = blockIdx.x, ntile = blockIdx.y;
    const int n = blockIdx.z % NN, grp = blockIdx.z / NN;
    const float* xg = grp ? g_s : g_t;
    const float* cg = grp ? c_g_s : c_g_t;
    float* og  = grp ? out4 : out2;
    float* ocg = grp ? out5 : out3;
    const int a_r = tid >> 2, a_c = (tid & 3) * 8;
    const int gr  = mtile * 64 + a_r;
    const bool mval = (gr < MR);
    const int ec = (gr * NN + n) * 256;
    const int w_r  = (tid >> 4) * 2;
    const int c0   = (tid & 15) * 4;
    const int gcol = ntile * 64 + c0;
    const int wave = tid >> 6, lane = tid & 63;
    const int lrow = lane & 15, lk = (lane >> 4) * 8;
    int aro[4];
    #pragma unroll
    for (int m = 0; m < 4; ++m) aro[m] = (m * 16 + lrow) * LDP + lk;
    const int brow = wave * 16 + lrow;
    const int bro  = brow * LDP + (lk ^ SWZ(brow));
    const int awo  = a_r * LDP + a_c;
    int bwo[4];
    #pragma unroll
    for (int j = 0; j < 4; ++j) bwo[j] = (c0 + j) * LDP + (w_r ^ SWZ(c0 + j));
    f32x4 acc[3][4];
    #pragma unroll
    for (int g = 0; g < 3; ++g)
        #pragma unroll
        for (int m = 0; m < 4; ++m) acc[g][m] = f32x4{0.f, 0.f, 0.f, 0.f};
    float4 alo, ahi, br0[3], br1[3];
    auto loadA = [&](int kt) {
        const int K0 = kt * 32, koff = (K0 & 255) + a_c;
        const float* src = ((K0 < 256) ? hn : xg) + ec + koff;
        alo = make_float4(0.f, 0.f, 0.f, 0.f); ahi = alo;
        if (mval) { alo = *(const float4*)src; ahi = *(const float4*)(src + 4); }
    };
    auto loadB = [&](int kt) {
        const int kw = kt * 32 + w_r;
        #pragma unroll
        for (int g = 0; g < 3; ++g) {
            const int gg6 = grp * 3 + g;
            const float* wrow = (kw < 256)
                ? Wg + (size_t)((gg6 * NN + n) * 256 + kw) * 256
                : Zg + (size_t)((gg6 * NN + n) * 256 + (kw - 256)) * 256;
            br0[g] = *(const float4*)(wrow + gcol);
            br1[g] = *(const float4*)(wrow + 256 + gcol);
        }
    };
    auto store = [&](int buf) {
        u16x8 aw;
        aw[0] = f2b(alo.x); aw[1] = f2b(alo.y); aw[2] = f2b(alo.z); aw[3] = f2b(alo.w);
        aw[4] = f2b(ahi.x); aw[5] = f2b(ahi.y); aw[6] = f2b(ahi.z); aw[7] = f2b(ahi.w);
        *(u16x8*)(&As2[buf][awo]) = aw;
        #pragma unroll
        for (int g = 0; g < 3; ++g) {
            u16* bb_ = &Bs2[buf][g * 64 * LDP];
            *(u32*)(&bb_[bwo[0]]) = pk2(br0[g].x, br1[g].x);
            *(u32*)(&bb_[bwo[1]]) = pk2(br0[g].y, br1[g].y);
            *(u32*)(&bb_[bwo[2]]) = pk2(br0[g].z, br1[g].z);
            *(u32*)(&bb_[bwo[3]]) = pk2(br0[g].w, br1[g].w);
        }
    };
    auto domfma = [&](int buf) {
        s16x8 af[4];
        #pragma unroll
        for (int m = 0; m < 4; ++m) af[m] = *(const s16x8*)(&As2[buf][aro[m]]);
        #pragma unroll
        for (int g = 0; g < 3; ++g) {
            const s16x8 bf = *(const s16x8*)(&Bs2[buf][g * 64 * LDP + bro]);
            #pragma unroll
            for (int m = 0; m < 4; ++m)
                acc[g][m] = __builtin_amdgcn_mfma_f32_16x16x32_bf16(af[m], bf, acc[g][m], 0, 0, 0);
        }
    };
    loadA(0); loadB(0); store(0);
    for (int kt = 0; kt < 16; kt += 2) {
        __syncthreads();
        loadA(kt + 1); loadB(kt + 1);
        domfma(0); store(1);
        __syncthreads();
        if (kt + 2 < 16) { loadA(kt + 2); loadB(kt + 2); }
        domfma(1);
        if (kt + 2 < 16) store(0);
    }
    const int col = ntile * 64 + wave * 16 + lrow;
    float bv[3];
    #pragma unroll
    for (int g = 0; g < 3; ++g) bv[g] = Bg[((grp * 3 + g) * NN + n) * 256 + col];
    #pragma unroll
    for (int m = 0; m < 4; ++m) {
        #pragma unroll
        for (int i = 0; i < 4; ++i) {
            const int row = mtile * 64 + m * 16 + (lane >> 4) * 4 + i;
            if (row < MR) {
                const size_t e = ((size_t)(row * NN + n)) * 256 + col;
                const float f    = sig_(acc[0][m][i] + bv[0]);
                const float cand = tanh_(acc[1][m][i] + bv[1]);
                const float o    = sig_(acc[2][m][i] + bv[2]);
                const float cn = f * cg[e] + (1.f - f) * cand;
                ocg[e] = cn;
                og[e]  = o * tanh_(cn);
            }
        }
    }
}

extern "C" void kernel_launch(void* const* d_in, const int* in_sizes, int n_in,
                              void* d_out, int out_size, void* d_ws, size_t ws_size,
                              hipStream_t stream)
{
    const float* h     = (const float*)d_in[0];
    const float* c_h   = (const float*)d_in[1];
    const float* p     = (const float*)d_in[2];
    const float* g_t   = (const float*)d_in[3];
    const float* c_g_t = (const float*)d_in[4];
    const float* g_s   = (const float*)d_in[5];
    const float* c_g_s = (const float*)d_in[6];
    const float* U     = (const float*)d_in[7];
    const float* Wt    = (const float*)d_in[8];
    const float* Ws    = (const float*)d_in[9];
    const float* Zt    = (const float*)d_in[10];
    const float* Zs    = (const float*)d_in[11];
    const float* bb    = (const float*)d_in[12];
    const float* Wg    = (const float*)d_in[13];
    const float* Zg    = (const float*)d_in[14];
    const float* bg    = (const float*)d_in[15];

    float* out0 = (float*)d_out;
    float* out1 = out0 + (size_t)SZT;
    float* out2 = out1 + (size_t)SZT;
    float* out3 = out2 + (size_t)SZT;
    float* out4 = out3 + (size_t)SZT;
    float* out5 = out4 + (size_t)SZT;

    dim3 blk(256);
    if (ws_size >= WS_NEED) {
        u16* wt0 = (u16*)d_ws;
        u16* wt1 = wt0 + WT0_ELEMS;
        wprep0<<<dim3(28, 4, 216), blk, 0, stream>>>(U, Wt, Ws, Zt, Zs, wt0);
        wprep1<<<dim3(8, 4, 144), blk, 0, stream>>>(Wg, Zg, wt1);

        hipFuncSetAttribute((const void*)fused_cell2,
                            hipFuncAttributeMaxDynamicSharedMemorySize, 81920);
        fused_cell2<<<dim3(13, 4, 24), blk, 81920, stream>>>(
            p, h, c_h, g_t, c_g_t, g_s, c_g_s, wt0, bb, out0, out1);
        fused_global2<<<dim3(13, 4, 48), blk, 0, stream>>>(
            out0, g_t, g_s, c_g_t, c_g_s, wt1, bg, out2, out3, out4, out5);
    } else {
        const int dynLds = 2 * (ABUF + BBUF) * (int)sizeof(u16);
        hipFuncSetAttribute((const void*)fused_cell_fb,
                            hipFuncAttributeMaxDynamicSharedMemorySize, dynLds);
        fused_cell_fb<<<dim3(13, 4, 24), blk, dynLds, stream>>>(
            p, h, c_h, g_t, c_g_t, g_s, c_g_s, U, Wt, Ws, Zt, Zs, bb, out0, out1);
        fused_global_fb<<<dim3(13, 4, 48), blk, 0, stream>>>(
            out0, g_t, g_s, c_g_t, c_g_s, Wg, Zg, bg, out2, out3, out4, out5);
    }
}

// Round 6
// 522.525 us; speedup vs baseline: 2.1698x; 1.2654x over previous
//
#include <hip/hip_runtime.h>
#include <hip/hip_bf16.h>

typedef unsigned short u16;
typedef u16 u16x8 __attribute__((ext_vector_type(8)));
typedef short s16x8 __attribute__((ext_vector_type(8)));
typedef float f32x4 __attribute__((ext_vector_type(4)));
typedef unsigned int u32;

#define NN 24
#define TT 49
#define MR 784                  // B*T = 16*49
#define SZT 4816896             // B*T*N*H

__device__ inline u16 f2b(float f){
    __hip_bfloat16 b = __float2bfloat16(f); u16 r; __builtin_memcpy(&r, &b, 2); return r;
}
__device__ inline float sig_(float x){ return 1.f / (1.f + __expf(-x)); }
__device__ inline float tanh_(float x){ float e = __expf(2.f * x); return (e - 1.f) / (e + 1.f); }

// ws layout (k-tiled): WT0 bf16 [216][56][256][32], WT1 bf16 [144][16][256][32]
#define WT0_ELEMS ((size_t)216 * 256 * 1792)
#define WT1_ELEMS ((size_t)144 * 256 * 512)
#define WS_NEED   ((WT0_ELEMS + WT1_ELEMS) * 2)

// ===========================================================================
// Prepass: weight f32 [k][col] -> bf16 k-tiled [kt][col][32], concat per slab.
// ===========================================================================
__global__ __launch_bounds__(256) void wprep0(
    const float* __restrict__ U,  const float* __restrict__ Wt,
    const float* __restrict__ Ws, const float* __restrict__ Zt,
    const float* __restrict__ Zs, u16* __restrict__ out)
{
    __shared__ u16 T[64][72];
    const int tid = threadIdx.x;
    const int kt = blockIdx.x, ct = blockIdx.y, z = blockIdx.z;
    const int n = z % NN, g = z / NN;
    const int k0 = kt * 64;

    const float* wbase;           // row k0 of the segment, 256-col rows
    if (k0 < 256)       wbase = U  + (size_t)((g * NN + n) * 256 + k0)          * 256;
    else if (k0 < 1024) wbase = Wt + (size_t)((g * NN + n) * 768 + (k0 - 256))  * 256;
    else if (k0 < 1280) wbase = Ws + (size_t)((g * NN + n) * 256 + (k0 - 1024)) * 256;
    else if (k0 < 1536) wbase = Zt + (size_t)((g * NN + n) * 256 + (k0 - 1280)) * 256;
    else { const int g2 = (g == 2) ? 1 : g;      // Zs_eff: f_ft uses Zs[lt]
           wbase = Zs + (size_t)((g2 * NN + n) * 256 + (k0 - 1536)) * 256; }

    const int colg = ct * 64 + (tid & 15) * 4;
    #pragma unroll
    for (int it = 0; it < 4; ++it) {
        const int krl = (tid >> 4) + it * 16;
        const float4 v = *(const float4*)(wbase + (size_t)krl * 256 + colg);
        const int cl = (tid & 15) * 4;
        T[cl + 0][krl] = f2b(v.x); T[cl + 1][krl] = f2b(v.y);
        T[cl + 2][krl] = f2b(v.z); T[cl + 3][krl] = f2b(v.w);
    }
    __syncthreads();
    const int col_l = tid >> 2, ks = (tid & 3) * 16;
    const int ktile = 2 * kt + (ks >> 5);          // global 32-k tile
    const int koff  = ks & 31;
    u16* dst = out + (size_t)z * 458752 + (size_t)ktile * 8192
                   + (size_t)(ct * 64 + col_l) * 32 + koff;
    u16x8 w0, w1;
    #pragma unroll
    for (int j = 0; j < 8; ++j) { w0[j] = T[col_l][ks + j]; w1[j] = T[col_l][ks + 8 + j]; }
    *(u16x8*)(dst) = w0; *(u16x8*)(dst + 8) = w1;
}

__global__ __launch_bounds__(256) void wprep1(
    const float* __restrict__ Wg, const float* __restrict__ Zg, u16* __restrict__ out)
{
    __shared__ u16 T[64][72];
    const int tid = threadIdx.x;
    const int kt = blockIdx.x, ct = blockIdx.y, z = blockIdx.z;
    const int k0 = kt * 64;
    const float* wbase = (k0 < 256)
        ? Wg + (size_t)(z * 256 + k0) * 256
        : Zg + (size_t)(z * 256 + (k0 - 256)) * 256;

    const int colg = ct * 64 + (tid & 15) * 4;
    #pragma unroll
    for (int it = 0; it < 4; ++it) {
        const int krl = (tid >> 4) + it * 16;
        const float4 v = *(const float4*)(wbase + (size_t)krl * 256 + colg);
        const int cl = (tid & 15) * 4;
        T[cl + 0][krl] = f2b(v.x); T[cl + 1][krl] = f2b(v.y);
        T[cl + 2][krl] = f2b(v.z); T[cl + 3][krl] = f2b(v.w);
    }
    __syncthreads();
    const int col_l = tid >> 2, ks = (tid & 3) * 16;
    const int ktile = 2 * kt + (ks >> 5);
    const int koff  = ks & 31;
    u16* dst = out + (size_t)z * 131072 + (size_t)ktile * 8192
                   + (size_t)(ct * 64 + col_l) * 32 + koff;
    u16x8 w0, w1;
    #pragma unroll
    for (int j = 0; j < 8; ++j) { w0[j] = T[col_l][ks + j]; w1[j] = T[col_l][ks + 8 + j]; }
    *(u16x8*)(dst) = w0; *(u16x8*)(dst + 8) = w1;
}

// ===========================================================================
// Phase 0: 64x64 tile, 9 gates, k-tiled bf16 weights, XCD-clustered blocks.
// LDS: dbuf A (64x32) + dbuf B (9x64x32), XOR slot swizzle. 81920 B dynamic.
// ===========================================================================
#define AB2 2048                 // elems per A buf
#define BB2 18432                // elems per B buf (9*2048)

__global__ __launch_bounds__(256, 2) void fused_cell2(
    const float* __restrict__ p,   const float* __restrict__ h,
    const float* __restrict__ c_h, const float* __restrict__ g_t,
    const float* __restrict__ c_g_t, const float* __restrict__ g_s,
    const float* __restrict__ c_g_s,
    const u16* __restrict__ WT0, const float* __restrict__ Bias,
    float* __restrict__ h_new, float* __restrict__ c_h_new)
{
    extern __shared__ u16 smem[];   // [A0|A1|B0|B1] = 40960 elems

    const int tid = threadIdx.x;
    // XCD-clustering decode: each (ntile,n) slab owned by exactly one XCD,
    // its 13 mtile-blocks temporally adjacent on that XCD (slab lives in L2).
    const int lin = blockIdx.x;
    const int xcd = lin & 7, j = lin >> 3;
    const int mtile = j % 13;
    const int slab  = (j / 13) * 8 + xcd;   // 0..95
    const int ntile = slab & 3, n = slab >> 2;

    // staging maps: thread -> (row/col = tid>>2, k-chunk = tid&3)
    const int s_r = tid >> 2, s_c = tid & 3;
    const int gr  = mtile * 64 + s_r;
    const bool mval = (gr < MR);
    const int ec = (gr * NN + n) * 256;
    const bool vnb = (n > 0), vna = (n < NN - 1), vtp = (gr % TT) != 0;

    // swizzled LDS write offset: row*32 + ((chunk ^ ((row>>1)&3))<<3)
    const int wro = s_r * 32 + ((s_c ^ ((s_r >> 1) & 3)) << 3);
    // B global (k-tiled): col*32 + chunk*8 within a kt-slice
    const size_t bgo = (size_t)(ntile * 64 + s_r) * 32 + s_c * 8;

    const int wave = tid >> 6, lane = tid & 63;
    const int lrow = lane & 15, lci = lane >> 4;

    int aro[4];
    #pragma unroll
    for (int m = 0; m < 4; ++m) {
        const int row = m * 16 + lrow;
        aro[m] = row * 32 + ((lci ^ ((row >> 1) & 3)) << 3);
    }
    const int colr = wave * 16 + lrow;
    const int bro  = colr * 32 + ((lci ^ ((colr >> 1) & 3)) << 3);

    f32x4 acc[9][4];
    #pragma unroll
    for (int g = 0; g < 9; ++g)
        #pragma unroll
        for (int m = 0; m < 4; ++m) acc[g][m] = f32x4{0.f, 0.f, 0.f, 0.f};

    float4 alo, ahi; u16x8 brw[9];

    auto loadA = [&](int kt) {
        const int K0 = kt * 32, seg = K0 >> 8, koff = (K0 & 255) + s_c * 8;
        const float* src = nullptr; bool valid = mval;
        switch (seg) {
            case 0: src = p + ec + koff; break;
            case 1: valid &= vnb; src = h + ec - 256 + koff; break;
            case 2: src = h + ec + koff; break;
            case 3: valid &= vna; src = h + ec + 256 + koff; break;
            case 4: valid &= vtp; src = h + ec - NN * 256 + koff; break;
            case 5: src = g_t + ec + koff; break;
            default: src = g_s + ec + koff; break;
        }
        alo = make_float4(0.f, 0.f, 0.f, 0.f); ahi = alo;
        if (valid) { alo = *(const float4*)src; ahi = *(const float4*)(src + 4); }
    };
    auto loadB = [&](int kt) {
        const u16* wb = WT0 + (size_t)n * 458752 + (size_t)kt * 8192 + bgo;
        #pragma unroll
        for (int g = 0; g < 9; ++g)
            brw[g] = *(const u16x8*)(wb + (size_t)g * 11010048);   // g*24*458752
    };
    auto store = [&](int buf) {
        u16* Asb = smem + buf * AB2;
        u16* Bsb = smem + 2 * AB2 + buf * BB2;
        u16x8 aw;
        aw[0] = f2b(alo.x); aw[1] = f2b(alo.y); aw[2] = f2b(alo.z); aw[3] = f2b(alo.w);
        aw[4] = f2b(ahi.x); aw[5] = f2b(ahi.y); aw[6] = f2b(ahi.z); aw[7] = f2b(ahi.w);
        *(u16x8*)(&Asb[wro]) = aw;
        #pragma unroll
        for (int g = 0; g < 9; ++g)
            *(u16x8*)(&Bsb[g * 2048 + wro]) = brw[g];
    };
    auto domfma = [&](int buf) {
        const u16* Asb = smem + buf * AB2;
        const u16* Bsb = smem + 2 * AB2 + buf * BB2;
        s16x8 af[4];
        #pragma unroll
        for (int m = 0; m < 4; ++m) af[m] = *(const s16x8*)(&Asb[aro[m]]);
        #pragma unroll
        for (int g = 0; g < 9; ++g) {
            const s16x8 bf = *(const s16x8*)(&Bsb[g * 2048 + bro]);
            #pragma unroll
            for (int m = 0; m < 4; ++m)
                acc[g][m] = __builtin_amdgcn_mfma_f32_16x16x32_bf16(af[m], bf, acc[g][m], 0, 0, 0);
        }
    };

    loadA(0); loadB(0); store(0);
    for (int kt = 0; kt < 56; kt += 2) {
        __syncthreads();
        loadA(kt + 1); loadB(kt + 1);
        domfma(0);
        store(1);
        __syncthreads();
        if (kt + 2 < 56) { loadA(kt + 2); loadB(kt + 2); }
        domfma(1);
        if (kt + 2 < 56) store(0);
    }

    // ---- epilogue: bias + cell update, f32 stores
    const int col = ntile * 64 + wave * 16 + lrow;
    float bv[9];
    #pragma unroll
    for (int g = 0; g < 9; ++g) bv[g] = Bias[(g * NN + n) * 256 + col];

    #pragma unroll
    for (int m = 0; m < 4; ++m) {
        #pragma unroll
        for (int i = 0; i < 4; ++i) {
            const int row = mtile * 64 + m * 16 + (lane >> 4) * 4 + i;
            if (row < MR) {
                const size_t e = ((size_t)(row * NN + n)) * 256 + col;
                const float i_n  = sig_(acc[0][m][i] + bv[0]);
                const float f_lt = sig_(acc[1][m][i] + bv[1]);
                const float f_ft = sig_(acc[2][m][i] + bv[2]);
                const float f_rt = sig_(acc[3][m][i] + bv[3]);
                const float f_s  = sig_(acc[4][m][i] + bv[4]);
                const float f_gt = sig_(acc[5][m][i] + bv[5]);
                const float f_gs = sig_(acc[6][m][i] + bv[6]);
                const float o_n  = sig_(acc[7][m][i] + bv[7]);
                const float c_n  = tanh_(acc[8][m][i] + bv[8]);
                const float cb = (n > 0)      ? c_h[e - 256] : 0.f;
                const float ca = (n < NN - 1) ? c_h[e + 256] : 0.f;
                const float cs = (row % TT)   ? c_h[e - NN * 256] : 0.f;
                const float cn = f_lt * cb + f_ft * c_h[e] + f_rt * ca
                               + f_s * cs + f_gt * c_g_t[e] + f_gs * c_g_s[e]
                               + i_n * c_n;
                c_h_new[e] = cn;
                h_new[e]   = o_n * tanh_(cn);
            }
        }
    }
}

// ===========================================================================
// Phase 1: 64x64 tile, 3 gates, K=512, k-tiled WT1, XCD-clustered. 32 KiB LDS.
// ===========================================================================
__global__ __launch_bounds__(256, 3) void fused_global2(
    const float* __restrict__ hn,   const float* __restrict__ g_t,
    const float* __restrict__ g_s,  const float* __restrict__ c_g_t,
    const float* __restrict__ c_g_s,
    const u16* __restrict__ WT1, const float* __restrict__ Bg,
    float* __restrict__ out2, float* __restrict__ out3,
    float* __restrict__ out4, float* __restrict__ out5)
{
    __shared__ u16 smem[2 * 2048 + 2 * 6144];

    const int tid = threadIdx.x;
    const int lin = blockIdx.x;
    const int xcd = lin & 7, j = lin >> 3;
    const int mtile = j % 13;
    const int slab  = (j / 13) * 8 + xcd;   // 0..191
    const int ntile = slab & 3;
    const int zz    = slab >> 2;            // 0..47
    const int n = zz % NN, grp = zz / NN;

    const float* xg = grp ? g_s : g_t;
    const float* cg = grp ? c_g_s : c_g_t;
    float* og  = grp ? out4 : out2;
    float* ocg = grp ? out5 : out3;

    const int s_r = tid >> 2, s_c = tid & 3;
    const int gr  = mtile * 64 + s_r;
    const bool mval = (gr < MR);
    const int ec = (gr * NN + n) * 256;

    const int wro = s_r * 32 + ((s_c ^ ((s_r >> 1) & 3)) << 3);
    const size_t bgo = (size_t)(ntile * 64 + s_r) * 32 + s_c * 8;

    const int wave = tid >> 6, lane = tid & 63;
    const int lrow = lane & 15, lci = lane >> 4;

    int aro[4];
    #pragma unroll
    for (int m = 0; m < 4; ++m) {
        const int row = m * 16 + lrow;
        aro[m] = row * 32 + ((lci ^ ((row >> 1) & 3)) << 3);
    }
    const int colr = wave * 16 + lrow;
    const int bro  = colr * 32 + ((lci ^ ((colr >> 1) & 3)) << 3);

    f32x4 acc[3][4];
    #pragma unroll
    for (int g = 0; g < 3; ++g)
        #pragma unroll
        for (int m = 0; m < 4; ++m) acc[g][m] = f32x4{0.f, 0.f, 0.f, 0.f};

    float4 alo, ahi; u16x8 brw[3];

    auto loadA = [&](int kt) {
        const int K0 = kt * 32, koff = (K0 & 255) + s_c * 8;
        const float* src = ((K0 < 256) ? hn : xg) + ec + koff;
        alo = make_float4(0.f, 0.f, 0.f, 0.f); ahi = alo;
        if (mval) { alo = *(const float4*)src; ahi = *(const float4*)(src + 4); }
    };
    auto loadB = [&](int kt) {
        const u16* wb = WT1 + (size_t)(grp * 3 * NN + n) * 131072
                            + (size_t)kt * 8192 + bgo;
        #pragma unroll
        for (int g = 0; g < 3; ++g)
            brw[g] = *(const u16x8*)(wb + (size_t)g * 3145728);    // g*24*131072
    };
    auto store = [&](int buf) {
        u16* Asb = smem + buf * 2048;
        u16* Bsb = smem + 2 * 2048 + buf * 6144;
        u16x8 aw;
        aw[0] = f2b(alo.x); aw[1] = f2b(alo.y); aw[2] = f2b(alo.z); aw[3] = f2b(alo.w);
        aw[4] = f2b(ahi.x); aw[5] = f2b(ahi.y); aw[6] = f2b(ahi.z); aw[7] = f2b(ahi.w);
        *(u16x8*)(&Asb[wro]) = aw;
        #pragma unroll
        for (int g = 0; g < 3; ++g)
            *(u16x8*)(&Bsb[g * 2048 + wro]) = brw[g];
    };
    auto domfma = [&](int buf) {
        const u16* Asb = smem + buf * 2048;
        const u16* Bsb = smem + 2 * 2048 + buf * 6144;
        s16x8 af[4];
        #pragma unroll
        for (int m = 0; m < 4; ++m) af[m] = *(const s16x8*)(&Asb[aro[m]]);
        #pragma unroll
        for (int g = 0; g < 3; ++g) {
            const s16x8 bf = *(const s16x8*)(&Bsb[g * 2048 + bro]);
            #pragma unroll
            for (int m = 0; m < 4; ++m)
                acc[g][m] = __builtin_amdgcn_mfma_f32_16x16x32_bf16(af[m], bf, acc[g][m], 0, 0, 0);
        }
    };

    loadA(0); loadB(0); store(0);
    for (int kt = 0; kt < 16; kt += 2) {
        __syncthreads();
        loadA(kt + 1); loadB(kt + 1);
        domfma(0);
        store(1);
        __syncthreads();
        if (kt + 2 < 16) { loadA(kt + 2); loadB(kt + 2); }
        domfma(1);
        if (kt + 2 < 16) store(0);
    }

    const int col = ntile * 64 + wave * 16 + lrow;
    float bv[3];
    #pragma unroll
    for (int g = 0; g < 3; ++g) bv[g] = Bg[((grp * 3 + g) * NN + n) * 256 + col];

    #pragma unroll
    for (int m = 0; m < 4; ++m) {
        #pragma unroll
        for (int i = 0; i < 4; ++i) {
            const int row = mtile * 64 + m * 16 + (lane >> 4) * 4 + i;
            if (row < MR) {
                const size_t e = ((size_t)(row * NN + n)) * 256 + col;
                const float f    = sig_(acc[0][m][i] + bv[0]);
                const float cand = tanh_(acc[1][m][i] + bv[1]);
                const float o    = sig_(acc[2][m][i] + bv[2]);
                const float cn = f * cg[e] + (1.f - f) * cand;
                ocg[e] = cn;
                og[e]  = o * tanh_(cn);
            }
        }
    }
}

extern "C" void kernel_launch(void* const* d_in, const int* in_sizes, int n_in,
                              void* d_out, int out_size, void* d_ws, size_t ws_size,
                              hipStream_t stream)
{
    const float* h     = (const float*)d_in[0];
    const float* c_h   = (const float*)d_in[1];
    const float* p     = (const float*)d_in[2];
    const float* g_t   = (const float*)d_in[3];
    const float* c_g_t = (const float*)d_in[4];
    const float* g_s   = (const float*)d_in[5];
    const float* c_g_s = (const float*)d_in[6];
    const float* U     = (const float*)d_in[7];
    const float* Wt    = (const float*)d_in[8];
    const float* Ws    = (const float*)d_in[9];
    const float* Zt    = (const float*)d_in[10];
    const float* Zs    = (const float*)d_in[11];
    const float* bb    = (const float*)d_in[12];
    const float* Wg    = (const float*)d_in[13];
    const float* Zg    = (const float*)d_in[14];
    const float* bg    = (const float*)d_in[15];

    float* out0 = (float*)d_out;        // h_new
    float* out1 = out0 + (size_t)SZT;   // c_h_new
    float* out2 = out1 + (size_t)SZT;   // g_t_new
    float* out3 = out2 + (size_t)SZT;   // c_g_t_new
    float* out4 = out3 + (size_t)SZT;   // g_s_new
    float* out5 = out4 + (size_t)SZT;   // c_g_s_new

    u16* wt0 = (u16*)d_ws;
    u16* wt1 = wt0 + WT0_ELEMS;

    dim3 blk(256);
    wprep0<<<dim3(28, 4, 216), blk, 0, stream>>>(U, Wt, Ws, Zt, Zs, wt0);
    wprep1<<<dim3(8, 4, 144), blk, 0, stream>>>(Wg, Zg, wt1);

    hipFuncSetAttribute((const void*)fused_cell2,
                        hipFuncAttributeMaxDynamicSharedMemorySize, 81920);
    fused_cell2<<<dim3(1248), blk, 81920, stream>>>(
        p, h, c_h, g_t, c_g_t, g_s, c_g_s, wt0, bb, out0, out1);
    fused_global2<<<dim3(2496), blk, 0, stream>>>(
        out0, g_t, g_s, c_g_t, c_g_s, wt1, bg, out2, out3, out4, out5);
}